// Round 3
// baseline (279.826 us; speedup 1.0000x reference)
//
#include <hip/hip_runtime.h>
#include <cstdint>
#include <cstring>

// ---------------------------------------------------------------------------
// Op list (built on host by replicating numpy's RNG stream, passed by value)
// op byte = (kind<<4) | (w0<<2) | w1
// kinds: 0 RX, 1 RY, 2 RZ, 3 CRX(ctrl=w0,tgt=w1), 4 H, 5 SX, 6 CNOT(ctrl=w0,tgt=w1)
// ---------------------------------------------------------------------------
struct OpList {
    unsigned char enc[8];
    unsigned char qfc[50];
};

// ------------------------- host-side numpy RNG replica ----------------------
namespace nprng {

typedef unsigned __int128 u128;

struct PCG {
    u128 state, inc;
    bool has32;
    uint32_t buf32;

    uint64_t next64() {
        const u128 mult = (((u128)2549297995355413924ULL) << 64) | (u128)4865540595714422341ULL;
        state = state * mult + inc;
        uint64_t hi = (uint64_t)(state >> 64), lo = (uint64_t)state;
        unsigned rot = (unsigned)(state >> 122) & 63u;
        uint64_t v = hi ^ lo;
        return (v >> rot) | (v << ((64u - rot) & 63u));
    }
    // pcg64_next32: persistent half-buffer
    uint32_t next32() {
        if (has32) { has32 = false; return buf32; }
        uint64_t n = next64();
        has32 = true;
        buf32 = (uint32_t)(n >> 32);
        return (uint32_t)n;
    }
};

// SeedSequence(entropy) -> generate_state(4, uint64) -> pcg64_set_seed
static void seed_pcg(PCG& g, uint32_t entropy) {
    const uint32_t INIT_A = 0x43b0d7e5u, MULT_A = 0x931e8875u;
    const uint32_t INIT_B = 0x8b51f9ddu, MULT_B = 0x58f38dedu;
    const uint32_t MIX_L = 0xca01f9ddu, MIX_R = 0x4973f715u;

    uint32_t pool[4];
    uint32_t hc = INIT_A;
    auto hashmix = [&hc](uint32_t v) -> uint32_t {
        v ^= hc; hc *= MULT_A; v *= hc; v ^= v >> 16; return v;
    };
    // numpy: mix(x,y) = (L*x - R*y) ^ >>16   (modular subtraction!)
    auto mix = [MIX_L, MIX_R](uint32_t x, uint32_t y) -> uint32_t {
        uint32_t r = MIX_L * x - MIX_R * y;
        r ^= r >> 16;
        return r;
    };
    pool[0] = hashmix(entropy);
    for (int i = 1; i < 4; ++i) pool[i] = hashmix(0u);
    for (int s = 0; s < 4; ++s)
        for (int d = 0; d < 4; ++d)
            if (s != d) pool[d] = mix(pool[d], hashmix(pool[s]));

    uint32_t hb = INIT_B;
    uint32_t w[8];
    for (int i = 0; i < 8; ++i) {
        uint32_t dv = pool[i & 3];
        dv ^= hb; hb *= MULT_B; dv *= hb; dv ^= dv >> 16;
        w[i] = dv;
    }
    uint64_t w64[4];
    for (int i = 0; i < 4; ++i)
        w64[i] = (uint64_t)w[2 * i] | ((uint64_t)w[2 * i + 1] << 32);

    u128 initstate = (((u128)w64[0]) << 64) | (u128)w64[1];
    u128 initseq   = (((u128)w64[2]) << 64) | (u128)w64[3];
    const u128 mult = (((u128)2549297995355413924ULL) << 64) | (u128)4865540595714422341ULL;
    g.state = 0;
    g.inc = (initseq << 1) | (u128)1;
    g.state = g.state * mult + g.inc;
    g.state += initstate;
    g.state = g.state * mult + g.inc;
    g.has32 = false;
    g.buf32 = 0;
}

// buffered_bounded_lemire_uint32: used by integers() (range fits 32-bit),
// choice-Floyd, and _shuffle_int. Persistent pcg64_next32 buffering.
static uint32_t lemire32(PCG& g, uint32_t rng) {
    uint64_t rng_excl = (uint64_t)rng + 1;
    uint64_t m = (uint64_t)g.next32() * rng_excl;
    uint32_t leftover = (uint32_t)m;
    if (leftover < (uint32_t)rng_excl) {
        uint32_t threshold = (uint32_t)((uint64_t)(0xFFFFFFFFu - rng) % rng_excl);
        while (leftover < threshold) {
            m = (uint64_t)g.next32() * rng_excl;
            leftover = (uint32_t)m;
        }
    }
    return (uint32_t)(m >> 32);
}

static void make_ops(uint32_t seed, int n, unsigned char* out) {
    PCG g;
    seed_pcg(g, seed);
    for (int i = 0; i < n; ++i) {
        uint32_t kind = lemire32(g, 3);  // integers(0,4) -> 32-bit Lemire path
        uint32_t w0, w1;
        if (kind == 3) {
            // choice(4, size=2, replace=False): Floyd (j=2 then j=3),
            // then _shuffle_int (one Lemire-32 draw, rng=1)
            uint32_t v2 = lemire32(g, 2);
            uint32_t v3 = lemire32(g, 3);
            uint32_t arr[2];
            arr[0] = v2;
            arr[1] = (v3 == v2) ? 3u : v3;
            uint32_t j = lemire32(g, 1);  // shuffle i=1: top bit of next32
            uint32_t t = arr[1]; arr[1] = arr[j]; arr[j] = t;
            w0 = arr[0]; w1 = arr[1];
        } else {
            w0 = lemire32(g, 3);  // integers(0,NQ)
            w1 = 0;
        }
        out[i] = (unsigned char)((kind << 4) | (w0 << 2) | w1);
    }
}

}  // namespace nprng

static OpList make_all_ops() {
    OpList o;
    nprng::make_ops(1u, 8, o.enc);
    nprng::make_ops(2u, 50, o.qfc);
    return o;
}

static const OpList g_ops = make_all_ops();  // built once at dlopen

// ---------------------------------------------------------------------------
// Kernel 1: conv1(1->8,3x3,SAME)+relu+pool2 -> LDS -> conv2(8->16)+relu+pool2
//           -> channel mean -> pm (B x 64). One block per image.
// ---------------------------------------------------------------------------
__global__ __launch_bounds__(256) void cnn_kernel(
    const float* __restrict__ x, const float* __restrict__ w1,
    const float* __restrict__ b1, const float* __restrict__ w2,
    const float* __restrict__ b2, float* __restrict__ pm)
{
    __shared__ float xs[32 * 33];        // padded stride 33
    __shared__ float h1s[8 * 16 * 18];   // padded stride 18
    __shared__ float w1s[72], b1s[8], w2s[1152], b2s[16];
    __shared__ float part[4][64];

    const int tid = threadIdx.x;
    const int b = blockIdx.x;
    const float* xb = x + (size_t)b * 1024;

    for (int k = tid; k < 1024; k += 256) xs[(k >> 5) * 33 + (k & 31)] = xb[k];
    for (int k = tid; k < 1152; k += 256) w2s[k] = w2[k];
    if (tid < 72) w1s[tid] = w1[tid];
    if (tid < 8) b1s[tid] = b1[tid];
    if (tid < 16) b2s[tid] = b2[tid];
    __syncthreads();

    // ---- conv1 + relu + pool: thread per pooled position (16x16) ----
    {
        const int i = tid >> 4, j = tid & 15;
        float patch[4][4];
#pragma unroll
        for (int u = 0; u < 4; ++u) {
            int r = 2 * i - 1 + u;
#pragma unroll
            for (int v = 0; v < 4; ++v) {
                int cc = 2 * j - 1 + v;
                patch[u][v] = (r >= 0 && r < 32 && cc >= 0 && cc < 32) ? xs[r * 33 + cc] : 0.f;
            }
        }
#pragma unroll
        for (int c = 0; c < 8; ++c) {
            float m = -3.4e38f;
#pragma unroll
            for (int di = 0; di < 2; ++di)
#pragma unroll
                for (int dj = 0; dj < 2; ++dj) {
                    float acc = b1s[c];
#pragma unroll
                    for (int u = 0; u < 3; ++u)
#pragma unroll
                        for (int v = 0; v < 3; ++v)
                            acc += w1s[c * 9 + u * 3 + v] * patch[di + u][dj + v];
                    m = fmaxf(m, acc);
                }
            h1s[c * 288 + i * 18 + j] = fmaxf(m, 0.f);
        }
    }
    __syncthreads();

    // ---- conv2 + relu + pool + channel-mean: thread per (cgroup, pooled 8x8) ----
    {
        const int pos = tid & 63, cb = tid >> 6;
        const int i = pos >> 3, j = pos & 7;
        float acc[4][2][2];
#pragma unroll
        for (int k = 0; k < 4; ++k) {
            float bb = b2s[cb * 4 + k];
            acc[k][0][0] = bb; acc[k][0][1] = bb; acc[k][1][0] = bb; acc[k][1][1] = bb;
        }
#pragma unroll
        for (int ci = 0; ci < 8; ++ci) {
            float patch[4][4];
#pragma unroll
            for (int u = 0; u < 4; ++u) {
                int r = 2 * i - 1 + u;
#pragma unroll
                for (int v = 0; v < 4; ++v) {
                    int cc = 2 * j - 1 + v;
                    patch[u][v] = (r >= 0 && r < 16 && cc >= 0 && cc < 16)
                                      ? h1s[ci * 288 + r * 18 + cc] : 0.f;
                }
            }
#pragma unroll
            for (int k = 0; k < 4; ++k) {
                const float* wp = &w2s[((cb * 4 + k) * 8 + ci) * 9];
#pragma unroll
                for (int di = 0; di < 2; ++di)
#pragma unroll
                    for (int dj = 0; dj < 2; ++dj)
#pragma unroll
                        for (int u = 0; u < 3; ++u)
#pragma unroll
                            for (int v = 0; v < 3; ++v)
                                acc[k][di][dj] += wp[u * 3 + v] * patch[di + u][dj + v];
            }
        }
        float sum = 0.f;
#pragma unroll
        for (int k = 0; k < 4; ++k) {
            float m = fmaxf(fmaxf(acc[k][0][0], acc[k][0][1]),
                            fmaxf(acc[k][1][0], acc[k][1][1]));
            sum += fmaxf(m, 0.f);
        }
        part[cb][pos] = sum;
    }
    __syncthreads();
    if (tid < 64) {
        float s = part[0][tid] + part[1][tid] + part[2][tid] + part[3][tid];
        pm[(size_t)b * 64 + tid] = s * (1.f / 16.f);
    }
}

// ---------------------------------------------------------------------------
// Kernel 2: build measurement matrices.
// Wire w lives at bit (3-w) of the 16-dim state index.
// ---------------------------------------------------------------------------
__device__ inline void apply_gate(float* Ur, float* Ui, int r, int c,
                                  int kind, int w0, int w1, float t)
{
    float nr, ni;
    const int idx = r * 16 + c;
    if (kind == 6) {  // CNOT ctrl w0, tgt w1
        int stc = 8 >> w0, stt = 8 >> w1;
        int src = (r & stc) ? (r ^ stt) : r;
        nr = Ur[src * 16 + c];
        ni = Ui[src * 16 + c];
    } else if (kind == 3) {  // CRX ctrl w0, tgt w1
        int stc = 8 >> w0, stt = 8 >> w1;
        if (!(r & stc)) { nr = Ur[idx]; ni = Ui[idx]; }
        else {
            float ch = cosf(0.5f * t), sh = sinf(0.5f * t);
            int i0 = (r & ~stt) * 16 + c, i1 = (r | stt) * 16 + c;
            float a0r = Ur[i0], a0i = Ui[i0], a1r = Ur[i1], a1i = Ui[i1];
            if (!(r & stt)) { nr = ch * a0r + sh * a1i; ni = ch * a0i - sh * a1r; }
            else            { nr = sh * a0i + ch * a1r; ni = -sh * a0r + ch * a1i; }
        }
    } else {  // single-qubit on w0
        int st = 8 >> w0;
        int i0 = (r & ~st) * 16 + c, i1 = (r | st) * 16 + c;
        float a0r = Ur[i0], a0i = Ui[i0], a1r = Ur[i1], a1i = Ui[i1];
        int bit = (r & st) ? 1 : 0;
        if (kind == 0) {  // RX
            float ch = cosf(0.5f * t), sh = sinf(0.5f * t);
            if (!bit) { nr = ch * a0r + sh * a1i; ni = ch * a0i - sh * a1r; }
            else      { nr = sh * a0i + ch * a1r; ni = -sh * a0r + ch * a1i; }
        } else if (kind == 1) {  // RY
            float ch = cosf(0.5f * t), sh = sinf(0.5f * t);
            if (!bit) { nr = ch * a0r - sh * a1r; ni = ch * a0i - sh * a1i; }
            else      { nr = sh * a0r + ch * a1r; ni = sh * a0i + ch * a1i; }
        } else if (kind == 2) {  // RZ: diag(e^{-it/2}, e^{+it/2})
            float ch = cosf(0.5f * t), sh = sinf(0.5f * t);
            if (!bit) { nr = ch * a0r + sh * a0i; ni = ch * a0i - sh * a0r; }
            else      { nr = ch * a1r - sh * a1i; ni = ch * a1i + sh * a1r; }
        } else if (kind == 4) {  // H
            const float rh = 0.70710678118654752f;
            if (!bit) { nr = rh * (a0r + a1r); ni = rh * (a0i + a1i); }
            else      { nr = rh * (a0r - a1r); ni = rh * (a0i - a1i); }
        } else {  // SX: 0.5*[[1+i,1-i],[1-i,1+i]]
            float su = bit ? -0.5f : 0.5f;
            nr = 0.5f * (a0r + a1r) - su * a0i + su * a1i;
            ni = 0.5f * (a0i + a1i) + su * a0r - su * a1r;
        }
    }
    __syncthreads();
    Ur[idx] = nr;
    Ui[idx] = ni;
    __syncthreads();
}

__global__ __launch_bounds__(256) void build_kernel(
    const float* __restrict__ encp, const float* __restrict__ qfcr,
    const float* __restrict__ qfcp, float* __restrict__ Mout, OpList ops)
{
    __shared__ float Ur[256], Ui[256];
    const int tid = threadIdx.x;
    const int r = tid >> 4, c = tid & 15;
    Ur[tid] = (r == c) ? 1.f : 0.f;
    Ui[tid] = 0.f;
    __syncthreads();

    for (int i = 0; i < 8; ++i) {
        int op = ops.enc[i];
        apply_gate(Ur, Ui, r, c, (op >> 4) & 7, (op >> 2) & 3, op & 3, encp[i]);
    }
    // M_enc[w] = Re(U^H Z_w U)
#pragma unroll
    for (int w = 0; w < 4; ++w) {
        float acc = 0.f;
        int bp = 3 - w;
        for (int k = 0; k < 16; ++k) {
            float z = ((k >> bp) & 1) ? -1.f : 1.f;
            acc += z * (Ur[k * 16 + r] * Ur[k * 16 + c] + Ui[k * 16 + r] * Ui[k * 16 + c]);
        }
        Mout[w * 256 + tid] = acc;
    }

    for (int i = 0; i < 50; ++i) {
        int op = ops.qfc[i];
        apply_gate(Ur, Ui, r, c, (op >> 4) & 7, (op >> 2) & 3, op & 3, qfcr[i]);
    }
    apply_gate(Ur, Ui, r, c, 0, 0, 0, qfcp[0]);  // RX wire0
    apply_gate(Ur, Ui, r, c, 1, 1, 0, qfcp[1]);  // RY wire1
    apply_gate(Ur, Ui, r, c, 2, 3, 0, qfcp[2]);  // RZ wire3
    apply_gate(Ur, Ui, r, c, 3, 0, 2, qfcp[3]);  // CRX ctrl0 tgt2
    apply_gate(Ur, Ui, r, c, 4, 3, 0, 0.f);      // H wire3
    apply_gate(Ur, Ui, r, c, 5, 2, 0, 0.f);      // SX wire2
    apply_gate(Ur, Ui, r, c, 6, 3, 0, 0.f);      // CNOT ctrl3 tgt0
#pragma unroll
    for (int w = 0; w < 4; ++w) {
        float acc = 0.f;
        int bp = 3 - w;
        for (int k = 0; k < 16; ++k) {
            float z = ((k >> bp) & 1) ? -1.f : 1.f;
            acc += z * (Ur[k * 16 + r] * Ur[k * 16 + c] + Ui[k * 16 + r] * Ui[k * 16 + c]);
        }
        Mout[1024 + w * 256 + tid] = acc;
    }
}

// ---------------------------------------------------------------------------
// Kernel 3: per-patch quantum features (thread = one patch)
// ---------------------------------------------------------------------------
__global__ __launch_bounds__(256) void quantum_kernel(
    const float* __restrict__ pm, const float* __restrict__ M,
    float* __restrict__ qfeat, float* __restrict__ qraw, int Bv)
{
    __shared__ float Ms[2048];
    const int tid = threadIdx.x;
    for (int k = tid; k < 2048; k += 256) Ms[k] = M[k];
    __syncthreads();

    const int gid = blockIdx.x * 256 + tid;
    const int b = gid >> 4, p = gid & 15;
    if (b >= Bv) return;
    const int pr = p >> 2, pc = p & 3;
    const float* pmb = pm + (size_t)b * 64;
    float d0 = pmb[(2 * pr) * 8 + 2 * pc];
    float d1 = pmb[(2 * pr) * 8 + 2 * pc + 1];
    float d2 = pmb[(2 * pr + 1) * 8 + 2 * pc];
    float d3 = pmb[(2 * pr + 1) * 8 + 2 * pc + 1];
    float f0c = cosf(0.5f * d0), f0s = sinf(0.5f * d0);
    float f1c = cosf(0.5f * d1), f1s = sinf(0.5f * d1);
    float f2c = cosf(0.5f * d2), f2s = sinf(0.5f * d2);
    float f3c = cosf(0.5f * d3), f3s = sinf(0.5f * d3);

    float amp[16];
#pragma unroll
    for (int k = 0; k < 16; ++k) {
        float v = ((k & 8) ? f0s : f0c);
        v *= ((k & 4) ? f1s : f1c);
        v *= ((k & 2) ? f2s : f2c);
        v *= ((k & 1) ? f3s : f3c);
        amp[k] = v;
    }

    float qv[4];
#pragma unroll
    for (int w = 0; w < 4; ++w) {
        float acc = 0.f;
        for (int i = 0; i < 16; ++i) {
            const float* Mr = &Ms[(w * 16 + i) * 16];
            float inner = 0.f;
#pragma unroll
            for (int j = 0; j < 16; ++j) inner += Mr[j] * amp[j];
            acc += amp[i] * inner;
        }
        qv[w] = acc;
    }
    *(float4*)(qfeat + (size_t)b * 64 + p * 4) = make_float4(qv[0], qv[1], qv[2], qv[3]);

    if (p == 15) {
        float qq[4];
#pragma unroll
        for (int w = 0; w < 4; ++w) {
            float acc = 0.f;
            for (int i = 0; i < 16; ++i) {
                const float* Mr = &Ms[1024 + (w * 16 + i) * 16];
                float inner = 0.f;
#pragma unroll
                for (int j = 0; j < 16; ++j) inner += Mr[j] * amp[j];
                acc += amp[i] * inner;
            }
            qq[w] = acc;
        }
        *(float4*)(qraw + (size_t)b * 4) = make_float4(qq[0], qq[1], qq[2], qq[3]);
    }
}

// ---------------------------------------------------------------------------
// Kernel 4: BN batch stats (one block)
// ---------------------------------------------------------------------------
__global__ __launch_bounds__(256) void bnstats_kernel(
    const float* __restrict__ qraw, float* __restrict__ stats, int Bv)
{
    __shared__ float red[256 * 8];
    const int tid = threadIdx.x;
    float s0 = 0, s1 = 0, s2 = 0, s3 = 0, q0 = 0, q1 = 0, q2 = 0, q3 = 0;
    for (int b = tid; b < Bv; b += 256) {
        float4 v = *(const float4*)(qraw + (size_t)b * 4);
        s0 += v.x; s1 += v.y; s2 += v.z; s3 += v.w;
        q0 += v.x * v.x; q1 += v.y * v.y; q2 += v.z * v.z; q3 += v.w * v.w;
    }
    red[tid * 8 + 0] = s0; red[tid * 8 + 1] = s1; red[tid * 8 + 2] = s2; red[tid * 8 + 3] = s3;
    red[tid * 8 + 4] = q0; red[tid * 8 + 5] = q1; red[tid * 8 + 6] = q2; red[tid * 8 + 7] = q3;
    __syncthreads();
    for (int off = 128; off > 0; off >>= 1) {
        if (tid < off)
            for (int k = 0; k < 8; ++k) red[tid * 8 + k] += red[(tid + off) * 8 + k];
        __syncthreads();
    }
    if (tid == 0) {
        float inv = 1.f / (float)Bv;
        for (int w = 0; w < 4; ++w) {
            float mu = red[w] * inv;
            float var = red[4 + w] * inv - mu * mu;
            stats[w] = mu;
            stats[4 + w] = var;
        }
    }
}

// ---------------------------------------------------------------------------
// Kernel 5: BN apply + FC(68->10) + log_softmax (thread = one sample)
// ---------------------------------------------------------------------------
__global__ __launch_bounds__(256) void head_kernel(
    const float* __restrict__ qfeat, const float* __restrict__ qraw,
    const float* __restrict__ stats, const float* __restrict__ gam,
    const float* __restrict__ bet, const float* __restrict__ fcw,
    const float* __restrict__ fcb, float* __restrict__ out, int Bv)
{
    __shared__ float Wf[680];
    __shared__ float bf[10], st[8], ga[4], be[4];
    const int tid = threadIdx.x;
    for (int k = tid; k < 680; k += 256) Wf[k] = fcw[k];
    if (tid < 10) bf[tid] = fcb[tid];
    if (tid < 8) st[tid] = stats[tid];
    if (tid < 4) { ga[tid] = gam[tid]; be[tid] = bet[tid]; }
    __syncthreads();

    const int b = blockIdx.x * 256 + tid;
    if (b >= Bv) return;

    float logit[10];
#pragma unroll
    for (int k = 0; k < 10; ++k) logit[k] = bf[k];

    const float* qf = qfeat + (size_t)b * 64;
    for (int j = 0; j < 64; ++j) {
        float v = qf[j];
#pragma unroll
        for (int k = 0; k < 10; ++k) logit[k] += v * Wf[k * 68 + j];
    }
    float4 qr = *(const float4*)(qraw + (size_t)b * 4);
    float qn[4] = {qr.x, qr.y, qr.z, qr.w};
#pragma unroll
    for (int w = 0; w < 4; ++w) {
        float v = (qn[w] - st[w]) / sqrtf(st[4 + w] + 1e-5f) * ga[w] + be[w];
#pragma unroll
        for (int k = 0; k < 10; ++k) logit[k] += v * Wf[k * 68 + 64 + w];
    }

    float m = logit[0];
#pragma unroll
    for (int k = 1; k < 10; ++k) m = fmaxf(m, logit[k]);
    float sum = 0.f;
#pragma unroll
    for (int k = 0; k < 10; ++k) sum += expf(logit[k] - m);
    float lse = logf(sum);
#pragma unroll
    for (int k = 0; k < 10; ++k) out[(size_t)b * 10 + k] = logit[k] - m - lse;
}

// ---------------------------------------------------------------------------
extern "C" void kernel_launch(void* const* d_in, const int* in_sizes, int n_in,
                              void* d_out, int out_size, void* d_ws, size_t ws_size,
                              hipStream_t stream)
{
    const float* x    = (const float*)d_in[0];
    const float* w1   = (const float*)d_in[1];
    const float* b1   = (const float*)d_in[2];
    const float* w2   = (const float*)d_in[3];
    const float* b2   = (const float*)d_in[4];
    const float* encp = (const float*)d_in[5];
    const float* qfcr = (const float*)d_in[6];
    const float* qfcp = (const float*)d_in[7];
    const float* gam  = (const float*)d_in[8];
    const float* bet  = (const float*)d_in[9];
    const float* fcw  = (const float*)d_in[10];
    const float* fcb  = (const float*)d_in[11];
    float* out = (float*)d_out;

    const int Bv = in_sizes[0] / 1024;  // 4096

    float* pm    = (float*)d_ws;                 // Bv*64
    float* qfeat = pm + (size_t)Bv * 64;         // Bv*64
    float* qraw  = qfeat + (size_t)Bv * 64;      // Bv*4
    float* Mmat  = qraw + (size_t)Bv * 4;        // 2048
    float* stats = Mmat + 2048;                  // 8

    cnn_kernel<<<Bv, 256, 0, stream>>>(x, w1, b1, w2, b2, pm);
    build_kernel<<<1, 256, 0, stream>>>(encp, qfcr, qfcp, Mmat, g_ops);
    quantum_kernel<<<(Bv * 16 + 255) / 256, 256, 0, stream>>>(pm, Mmat, qfeat, qraw, Bv);
    bnstats_kernel<<<1, 256, 0, stream>>>(qraw, stats, Bv);
    head_kernel<<<(Bv + 255) / 256, 256, 0, stream>>>(qfeat, qraw, stats, gam, bet,
                                                      fcw, fcb, out, Bv);
}

// Round 4
// 188.106 us; speedup vs baseline: 1.4876x; 1.4876x over previous
//
#include <hip/hip_runtime.h>
#include <cstdint>
#include <cstring>

// ---------------------------------------------------------------------------
// Op list (built on host by replicating numpy's RNG stream, passed by value)
// op byte = (kind<<4) | (w0<<2) | w1
// kinds: 0 RX, 1 RY, 2 RZ, 3 CRX(ctrl=w0,tgt=w1), 4 H, 5 SX, 6 CNOT(ctrl=w0,tgt=w1)
// ---------------------------------------------------------------------------
struct OpList {
    unsigned char enc[8];
    unsigned char qfc[50];
};

// ------------------------- host-side numpy RNG replica ----------------------
namespace nprng {

typedef unsigned __int128 u128;

struct PCG {
    u128 state, inc;
    bool has32;
    uint32_t buf32;

    uint64_t next64() {
        const u128 mult = (((u128)2549297995355413924ULL) << 64) | (u128)4865540595714422341ULL;
        state = state * mult + inc;
        uint64_t hi = (uint64_t)(state >> 64), lo = (uint64_t)state;
        unsigned rot = (unsigned)(state >> 122) & 63u;
        uint64_t v = hi ^ lo;
        return (v >> rot) | (v << ((64u - rot) & 63u));
    }
    // pcg64_next32: persistent half-buffer
    uint32_t next32() {
        if (has32) { has32 = false; return buf32; }
        uint64_t n = next64();
        has32 = true;
        buf32 = (uint32_t)(n >> 32);
        return (uint32_t)n;
    }
};

// SeedSequence(entropy) -> generate_state(4, uint64) -> pcg64_set_seed
static void seed_pcg(PCG& g, uint32_t entropy) {
    const uint32_t INIT_A = 0x43b0d7e5u, MULT_A = 0x931e8875u;
    const uint32_t INIT_B = 0x8b51f9ddu, MULT_B = 0x58f38dedu;
    const uint32_t MIX_L = 0xca01f9ddu, MIX_R = 0x4973f715u;

    uint32_t pool[4];
    uint32_t hc = INIT_A;
    auto hashmix = [&hc](uint32_t v) -> uint32_t {
        v ^= hc; hc *= MULT_A; v *= hc; v ^= v >> 16; return v;
    };
    // numpy: mix(x,y) = (L*x - R*y) ^ >>16   (modular subtraction!)
    auto mix = [MIX_L, MIX_R](uint32_t x, uint32_t y) -> uint32_t {
        uint32_t r = MIX_L * x - MIX_R * y;
        r ^= r >> 16;
        return r;
    };
    pool[0] = hashmix(entropy);
    for (int i = 1; i < 4; ++i) pool[i] = hashmix(0u);
    for (int s = 0; s < 4; ++s)
        for (int d = 0; d < 4; ++d)
            if (s != d) pool[d] = mix(pool[d], hashmix(pool[s]));

    uint32_t hb = INIT_B;
    uint32_t w[8];
    for (int i = 0; i < 8; ++i) {
        uint32_t dv = pool[i & 3];
        dv ^= hb; hb *= MULT_B; dv *= hb; dv ^= dv >> 16;
        w[i] = dv;
    }
    uint64_t w64[4];
    for (int i = 0; i < 4; ++i)
        w64[i] = (uint64_t)w[2 * i] | ((uint64_t)w[2 * i + 1] << 32);

    u128 initstate = (((u128)w64[0]) << 64) | (u128)w64[1];
    u128 initseq   = (((u128)w64[2]) << 64) | (u128)w64[3];
    const u128 mult = (((u128)2549297995355413924ULL) << 64) | (u128)4865540595714422341ULL;
    g.state = 0;
    g.inc = (initseq << 1) | (u128)1;
    g.state = g.state * mult + g.inc;
    g.state += initstate;
    g.state = g.state * mult + g.inc;
    g.has32 = false;
    g.buf32 = 0;
}

// buffered_bounded_lemire_uint32: used by integers() (range fits 32-bit),
// choice-Floyd, and _shuffle_int. Persistent pcg64_next32 buffering.
static uint32_t lemire32(PCG& g, uint32_t rng) {
    uint64_t rng_excl = (uint64_t)rng + 1;
    uint64_t m = (uint64_t)g.next32() * rng_excl;
    uint32_t leftover = (uint32_t)m;
    if (leftover < (uint32_t)rng_excl) {
        uint32_t threshold = (uint32_t)((uint64_t)(0xFFFFFFFFu - rng) % rng_excl);
        while (leftover < threshold) {
            m = (uint64_t)g.next32() * rng_excl;
            leftover = (uint32_t)m;
        }
    }
    return (uint32_t)(m >> 32);
}

static void make_ops(uint32_t seed, int n, unsigned char* out) {
    PCG g;
    seed_pcg(g, seed);
    for (int i = 0; i < n; ++i) {
        uint32_t kind = lemire32(g, 3);  // integers(0,4) -> 32-bit Lemire path
        uint32_t w0, w1;
        if (kind == 3) {
            uint32_t v2 = lemire32(g, 2);
            uint32_t v3 = lemire32(g, 3);
            uint32_t arr[2];
            arr[0] = v2;
            arr[1] = (v3 == v2) ? 3u : v3;
            uint32_t j = lemire32(g, 1);  // shuffle i=1
            uint32_t t = arr[1]; arr[1] = arr[j]; arr[j] = t;
            w0 = arr[0]; w1 = arr[1];
        } else {
            w0 = lemire32(g, 3);  // integers(0,NQ)
            w1 = 0;
        }
        out[i] = (unsigned char)((kind << 4) | (w0 << 2) | w1);
    }
}

}  // namespace nprng

static OpList make_all_ops() {
    OpList o;
    nprng::make_ops(1u, 8, o.enc);
    nprng::make_ops(2u, 50, o.qfc);
    return o;
}

static const OpList g_ops = make_all_ops();  // built once at dlopen

// ---------------------------------------------------------------------------
// LDS layout constants (even/odd column split, bank-conflict-free skews)
// xs: plane p in {even,odd cols}, rows -1..32 stored +1 (34), col-idx 0..16,
//     row stride 24 (2*24 == 16 mod 32 -> 4 i-rows x 16 j lanes tile 2-way).
// h1: per (ch,plane): rows -1..16 stored +1 (18), col-idx 0..8,
//     row stride 10 (2*10 == 20 mod 32 -> 8 i2 x 8 j2 lanes tile 2-way).
// ---------------------------------------------------------------------------
#define XS_STRIDE 24
#define XS_PLANE  (34 * XS_STRIDE)     // 816
#define XS_TOT    (2 * XS_PLANE)       // 1632
#define H1_STRIDE 10
#define H1_PLANE  (18 * H1_STRIDE)     // 180
#define H1_TOT    (16 * H1_PLANE)      // 2880  (8 ch x 2 planes)

// ---------------------------------------------------------------------------
// Kernel 1: conv1(1->8,3x3,SAME)+relu+pool2 -> LDS -> conv2(8->16)+relu+pool2
//           -> channel mean -> pm (B x 64). One block per image.
// ---------------------------------------------------------------------------
__global__ __launch_bounds__(256, 4) void cnn_kernel(
    const float* __restrict__ x, const float* __restrict__ w1,
    const float* __restrict__ b1, const float* __restrict__ w2,
    const float* __restrict__ b2, float* __restrict__ pm,
    float* __restrict__ stats)
{
    __shared__ float xs[XS_TOT];
    __shared__ float h1s[H1_TOT];
    __shared__ float w1s[72], b1s[8], w2s[1152], b2s[16];
    __shared__ float part[256];

    const int tid = threadIdx.x;
    const int b = blockIdx.x;
    const float* xb = x + (size_t)b * 1024;

    // zero halos (zero everything; interior overwritten after barrier)
    for (int k = tid; k < XS_TOT; k += 256) xs[k] = 0.f;
    for (int k = tid; k < H1_TOT; k += 256) h1s[k] = 0.f;
    for (int k = tid; k < 1152; k += 256) w2s[k] = w2[k];
    if (tid < 72) w1s[tid] = w1[tid];
    if (tid < 8) b1s[tid] = b1[tid];
    if (tid < 16) b2s[tid] = b2[tid];
    if (b == 0 && tid < 8) stats[tid] = 0.f;  // zero BN accumulators (pre-quantum)
    __syncthreads();

    // fill xs interior: col c -> plane c&1, idx: even c/2, odd (c+1)/2
    for (int k = tid; k < 1024; k += 256) {
        int r = k >> 5, c = k & 31;
        int p = c & 1;
        int q = p ? ((c + 1) >> 1) : (c >> 1);
        xs[p * XS_PLANE + (r + 1) * XS_STRIDE + q] = xb[k];
    }
    __syncthreads();

    // ---- conv1 + relu + pool: thread per pooled position (16x16) ----
    {
        const int i = tid >> 4, j = tid & 15;
        float patch[4][4];
#pragma unroll
        for (int u = 0; u < 4; ++u) {
            int r = 2 * i + u;  // stored row for input row 2i-1+u
            const float* ev = &xs[r * XS_STRIDE + j];
            const float* od = &xs[XS_PLANE + r * XS_STRIDE + j];
            patch[u][0] = od[0];  // col 2j-1
            patch[u][1] = ev[0];  // col 2j
            patch[u][2] = od[1];  // col 2j+1
            patch[u][3] = ev[1];  // col 2j+2
        }
        const int p = j & 1;
        const int q = p ? ((j + 1) >> 1) : (j >> 1);
#pragma unroll
        for (int c = 0; c < 8; ++c) {
            float m = -3.4e38f;
#pragma unroll
            for (int di = 0; di < 2; ++di)
#pragma unroll
                for (int dj = 0; dj < 2; ++dj) {
                    float acc = b1s[c];
#pragma unroll
                    for (int u = 0; u < 3; ++u)
#pragma unroll
                        for (int v = 0; v < 3; ++v)
                            acc += w1s[c * 9 + u * 3 + v] * patch[di + u][dj + v];
                    m = fmaxf(m, acc);
                }
            h1s[(c * 2 + p) * H1_PLANE + (i + 1) * H1_STRIDE + q] = fmaxf(m, 0.f);
        }
    }
    __syncthreads();

    // ---- conv2 + relu + pool + channel-mean ----
    {
        const int pos = tid & 63, cb = tid >> 6;
        const int i2 = pos >> 3, j2 = pos & 7;
        float acc[4][2][2];
#pragma unroll
        for (int k = 0; k < 4; ++k) {
            float bb = b2s[cb * 4 + k];
            acc[k][0][0] = bb; acc[k][0][1] = bb; acc[k][1][0] = bb; acc[k][1][1] = bb;
        }
#pragma unroll
        for (int ci = 0; ci < 8; ++ci) {
            float patch[4][4];
#pragma unroll
            for (int u = 0; u < 4; ++u) {
                int r = 2 * i2 + u;  // stored row for input row 2i2-1+u
                const float* ev = &h1s[(ci * 2 + 0) * H1_PLANE + r * H1_STRIDE + j2];
                const float* od = &h1s[(ci * 2 + 1) * H1_PLANE + r * H1_STRIDE + j2];
                patch[u][0] = od[0];  // col 2j2-1
                patch[u][1] = ev[0];  // col 2j2
                patch[u][2] = od[1];  // col 2j2+1
                patch[u][3] = ev[1];  // col 2j2+2
            }
#pragma unroll
            for (int k = 0; k < 4; ++k) {
                const float* wp = &w2s[((cb * 4 + k) * 8 + ci) * 9];
#pragma unroll
                for (int di = 0; di < 2; ++di)
#pragma unroll
                    for (int dj = 0; dj < 2; ++dj)
#pragma unroll
                        for (int u = 0; u < 3; ++u)
#pragma unroll
                            for (int v = 0; v < 3; ++v)
                                acc[k][di][dj] += wp[u * 3 + v] * patch[di + u][dj + v];
            }
        }
        float sum = 0.f;
#pragma unroll
        for (int k = 0; k < 4; ++k) {
            float m = fmaxf(fmaxf(acc[k][0][0], acc[k][0][1]),
                            fmaxf(acc[k][1][0], acc[k][1][1]));
            sum += fmaxf(m, 0.f);
        }
        part[cb * 64 + pos] = sum;
    }
    __syncthreads();
    if (tid < 64) {
        float s = part[tid] + part[64 + tid] + part[128 + tid] + part[192 + tid];
        pm[(size_t)b * 64 + tid] = s * (1.f / 16.f);
    }
}

// ---------------------------------------------------------------------------
// Gate application on 16x16 unitary held in LDS (one thread per element).
// Wire w lives at bit (3-w) of the state index.
// ---------------------------------------------------------------------------
__device__ inline void apply_gate(float* Ur, float* Ui, int r, int c,
                                  int kind, int w0, int w1, float t)
{
    float nr, ni;
    const int idx = r * 16 + c;
    if (kind == 6) {  // CNOT ctrl w0, tgt w1
        int stc = 8 >> w0, stt = 8 >> w1;
        int src = (r & stc) ? (r ^ stt) : r;
        nr = Ur[src * 16 + c];
        ni = Ui[src * 16 + c];
    } else if (kind == 3) {  // CRX ctrl w0, tgt w1
        int stc = 8 >> w0, stt = 8 >> w1;
        if (!(r & stc)) { nr = Ur[idx]; ni = Ui[idx]; }
        else {
            float ch = cosf(0.5f * t), sh = sinf(0.5f * t);
            int i0 = (r & ~stt) * 16 + c, i1 = (r | stt) * 16 + c;
            float a0r = Ur[i0], a0i = Ui[i0], a1r = Ur[i1], a1i = Ui[i1];
            if (!(r & stt)) { nr = ch * a0r + sh * a1i; ni = ch * a0i - sh * a1r; }
            else            { nr = sh * a0i + ch * a1r; ni = -sh * a0r + ch * a1i; }
        }
    } else {  // single-qubit on w0
        int st = 8 >> w0;
        int i0 = (r & ~st) * 16 + c, i1 = (r | st) * 16 + c;
        float a0r = Ur[i0], a0i = Ui[i0], a1r = Ur[i1], a1i = Ui[i1];
        int bit = (r & st) ? 1 : 0;
        if (kind == 0) {  // RX
            float ch = cosf(0.5f * t), sh = sinf(0.5f * t);
            if (!bit) { nr = ch * a0r + sh * a1i; ni = ch * a0i - sh * a1r; }
            else      { nr = sh * a0i + ch * a1r; ni = -sh * a0r + ch * a1i; }
        } else if (kind == 1) {  // RY
            float ch = cosf(0.5f * t), sh = sinf(0.5f * t);
            if (!bit) { nr = ch * a0r - sh * a1r; ni = ch * a0i - sh * a1i; }
            else      { nr = sh * a0r + ch * a1r; ni = sh * a0i + ch * a1i; }
        } else if (kind == 2) {  // RZ
            float ch = cosf(0.5f * t), sh = sinf(0.5f * t);
            if (!bit) { nr = ch * a0r + sh * a0i; ni = ch * a0i - sh * a0r; }
            else      { nr = ch * a1r - sh * a1i; ni = ch * a1i + sh * a1r; }
        } else if (kind == 4) {  // H
            const float rh = 0.70710678118654752f;
            if (!bit) { nr = rh * (a0r + a1r); ni = rh * (a0i + a1i); }
            else      { nr = rh * (a0r - a1r); ni = rh * (a0i - a1i); }
        } else {  // SX
            float su = bit ? -0.5f : 0.5f;
            nr = 0.5f * (a0r + a1r) - su * a0i + su * a1i;
            ni = 0.5f * (a0i + a1i) + su * a0r - su * a1r;
        }
    }
    __syncthreads();
    Ur[idx] = nr;
    Ui[idx] = ni;
    __syncthreads();
}

// ---------------------------------------------------------------------------
// Kernel 2: per-block gate build (phase A) + per-patch quantum features
//           (phase B) + block-reduced BN-stat atomics. Thread = one patch.
// ---------------------------------------------------------------------------
__global__ __launch_bounds__(256, 4) void quantum_kernel(
    const float* __restrict__ pm, const float* __restrict__ encp,
    const float* __restrict__ qfcr, const float* __restrict__ qfcp,
    float* __restrict__ qfeat, float* __restrict__ qraw,
    float* __restrict__ stats, int Bv, OpList ops)
{
    __shared__ float Ms[2048];
    __shared__ float Ur[256], Ui[256];
    __shared__ float prm[64];
    __shared__ float rstat[128];  // 8 stats x 16 contributors

    const int tid = threadIdx.x;
    if (tid < 8) prm[tid] = encp[tid];
    else if (tid < 58) prm[tid] = qfcr[tid - 8];
    else if (tid < 62) prm[tid] = qfcp[tid - 58];

    const int r = tid >> 4, c = tid & 15;
    Ur[tid] = (r == c) ? 1.f : 0.f;
    Ui[tid] = 0.f;
    __syncthreads();

    // ---- phase A: build both measurement-matrix sets in LDS ----
    for (int i = 0; i < 8; ++i) {
        int op = ops.enc[i];
        apply_gate(Ur, Ui, r, c, (op >> 4) & 7, (op >> 2) & 3, op & 3, prm[i]);
    }
#pragma unroll
    for (int w = 0; w < 4; ++w) {
        float acc = 0.f;
        int bp = 3 - w;
        for (int k = 0; k < 16; ++k) {
            float z = ((k >> bp) & 1) ? -1.f : 1.f;
            acc += z * (Ur[k * 16 + r] * Ur[k * 16 + c] + Ui[k * 16 + r] * Ui[k * 16 + c]);
        }
        Ms[w * 256 + tid] = acc;
    }
    for (int i = 0; i < 50; ++i) {
        int op = ops.qfc[i];
        apply_gate(Ur, Ui, r, c, (op >> 4) & 7, (op >> 2) & 3, op & 3, prm[8 + i]);
    }
    apply_gate(Ur, Ui, r, c, 0, 0, 0, prm[58]);  // RX wire0
    apply_gate(Ur, Ui, r, c, 1, 1, 0, prm[59]);  // RY wire1
    apply_gate(Ur, Ui, r, c, 2, 3, 0, prm[60]);  // RZ wire3
    apply_gate(Ur, Ui, r, c, 3, 0, 2, prm[61]);  // CRX ctrl0 tgt2
    apply_gate(Ur, Ui, r, c, 4, 3, 0, 0.f);      // H wire3
    apply_gate(Ur, Ui, r, c, 5, 2, 0, 0.f);      // SX wire2
    apply_gate(Ur, Ui, r, c, 6, 3, 0, 0.f);      // CNOT ctrl3 tgt0
#pragma unroll
    for (int w = 0; w < 4; ++w) {
        float acc = 0.f;
        int bp = 3 - w;
        for (int k = 0; k < 16; ++k) {
            float z = ((k >> bp) & 1) ? -1.f : 1.f;
            acc += z * (Ur[k * 16 + r] * Ur[k * 16 + c] + Ui[k * 16 + r] * Ui[k * 16 + c]);
        }
        Ms[1024 + w * 256 + tid] = acc;
    }
    __syncthreads();

    // ---- phase B: per-patch features ----
    const int gid = blockIdx.x * 256 + tid;
    const int b = gid >> 4, p = gid & 15;
    float qq[4] = {0.f, 0.f, 0.f, 0.f};
    bool last = false;
    if (b < Bv) {
        const int pr = p >> 2, pc = p & 3;
        const float* pmb = pm + (size_t)b * 64;
        float d0 = pmb[(2 * pr) * 8 + 2 * pc];
        float d1 = pmb[(2 * pr) * 8 + 2 * pc + 1];
        float d2 = pmb[(2 * pr + 1) * 8 + 2 * pc];
        float d3 = pmb[(2 * pr + 1) * 8 + 2 * pc + 1];
        float f0c = cosf(0.5f * d0), f0s = sinf(0.5f * d0);
        float f1c = cosf(0.5f * d1), f1s = sinf(0.5f * d1);
        float f2c = cosf(0.5f * d2), f2s = sinf(0.5f * d2);
        float f3c = cosf(0.5f * d3), f3s = sinf(0.5f * d3);

        float amp[16];
#pragma unroll
        for (int k = 0; k < 16; ++k) {
            float v = ((k & 8) ? f0s : f0c);
            v *= ((k & 4) ? f1s : f1c);
            v *= ((k & 2) ? f2s : f2c);
            v *= ((k & 1) ? f3s : f3c);
            amp[k] = v;
        }

        float qv[4];
#pragma unroll
        for (int w = 0; w < 4; ++w) {
            float acc = 0.f;
            for (int i = 0; i < 16; ++i) {
                const float* Mr = &Ms[(w * 16 + i) * 16];
                float inner = 0.f;
#pragma unroll
                for (int j = 0; j < 16; ++j) inner += Mr[j] * amp[j];
                acc += amp[i] * inner;
            }
            qv[w] = acc;
        }
        *(float4*)(qfeat + (size_t)b * 64 + p * 4) = make_float4(qv[0], qv[1], qv[2], qv[3]);

        if (p == 15) {
            last = true;
#pragma unroll
            for (int w = 0; w < 4; ++w) {
                float acc = 0.f;
                for (int i = 0; i < 16; ++i) {
                    const float* Mr = &Ms[1024 + (w * 16 + i) * 16];
                    float inner = 0.f;
#pragma unroll
                    for (int j = 0; j < 16; ++j) inner += Mr[j] * amp[j];
                    acc += amp[i] * inner;
                }
                qq[w] = acc;
            }
            *(float4*)(qraw + (size_t)b * 4) = make_float4(qq[0], qq[1], qq[2], qq[3]);
        }
    }

    // ---- block-level BN stat reduction -> one atomicAdd set per block ----
    for (int k = tid; k < 128; k += 256) rstat[k] = 0.f;
    __syncthreads();
    const int m = tid >> 4;  // contributor slot (one per b in this block)
    if (last) {
#pragma unroll
        for (int w = 0; w < 4; ++w) {
            rstat[w * 16 + m] = qq[w];
            rstat[64 + w * 16 + m] = qq[w] * qq[w];
        }
    }
    __syncthreads();
    if (tid < 8) {
        float s = 0.f;
#pragma unroll
        for (int k = 0; k < 16; ++k) s += rstat[tid * 16 + k];
        atomicAdd(&stats[tid], s);
    }
}

// ---------------------------------------------------------------------------
// Kernel 3: BN apply + FC(68->10) + log_softmax (thread = one sample)
// ---------------------------------------------------------------------------
__global__ __launch_bounds__(256) void head_kernel(
    const float* __restrict__ qfeat, const float* __restrict__ qraw,
    const float* __restrict__ stats, const float* __restrict__ gam,
    const float* __restrict__ bet, const float* __restrict__ fcw,
    const float* __restrict__ fcb, float* __restrict__ out, int Bv)
{
    __shared__ float Wf[680];
    __shared__ float bf[10], st[8], ga[4], be[4];
    const int tid = threadIdx.x;
    for (int k = tid; k < 680; k += 256) Wf[k] = fcw[k];
    if (tid < 10) bf[tid] = fcb[tid];
    if (tid < 8) st[tid] = stats[tid];
    if (tid < 4) { ga[tid] = gam[tid]; be[tid] = bet[tid]; }
    __syncthreads();

    const int b = blockIdx.x * 256 + tid;
    if (b >= Bv) return;

    const float invB = 1.f / (float)Bv;

    float logit[10];
#pragma unroll
    for (int k = 0; k < 10; ++k) logit[k] = bf[k];

    const float* qf = qfeat + (size_t)b * 64;
    for (int j = 0; j < 64; ++j) {
        float v = qf[j];
#pragma unroll
        for (int k = 0; k < 10; ++k) logit[k] += v * Wf[k * 68 + j];
    }
    float4 qr = *(const float4*)(qraw + (size_t)b * 4);
    float qn[4] = {qr.x, qr.y, qr.z, qr.w};
#pragma unroll
    for (int w = 0; w < 4; ++w) {
        float mu = st[w] * invB;
        float var = st[4 + w] * invB - mu * mu;
        float v = (qn[w] - mu) / sqrtf(var + 1e-5f) * ga[w] + be[w];
#pragma unroll
        for (int k = 0; k < 10; ++k) logit[k] += v * Wf[k * 68 + 64 + w];
    }

    float m = logit[0];
#pragma unroll
    for (int k = 1; k < 10; ++k) m = fmaxf(m, logit[k]);
    float sum = 0.f;
#pragma unroll
    for (int k = 0; k < 10; ++k) sum += expf(logit[k] - m);
    float lse = logf(sum);
#pragma unroll
    for (int k = 0; k < 10; ++k) out[(size_t)b * 10 + k] = logit[k] - m - lse;
}

// ---------------------------------------------------------------------------
extern "C" void kernel_launch(void* const* d_in, const int* in_sizes, int n_in,
                              void* d_out, int out_size, void* d_ws, size_t ws_size,
                              hipStream_t stream)
{
    const float* x    = (const float*)d_in[0];
    const float* w1   = (const float*)d_in[1];
    const float* b1   = (const float*)d_in[2];
    const float* w2   = (const float*)d_in[3];
    const float* b2   = (const float*)d_in[4];
    const float* encp = (const float*)d_in[5];
    const float* qfcr = (const float*)d_in[6];
    const float* qfcp = (const float*)d_in[7];
    const float* gam  = (const float*)d_in[8];
    const float* bet  = (const float*)d_in[9];
    const float* fcw  = (const float*)d_in[10];
    const float* fcb  = (const float*)d_in[11];
    float* out = (float*)d_out;

    const int Bv = in_sizes[0] / 1024;  // 4096

    float* pm    = (float*)d_ws;                 // Bv*64
    float* qfeat = pm + (size_t)Bv * 64;         // Bv*64
    float* qraw  = qfeat + (size_t)Bv * 64;      // Bv*4
    float* stats = qraw + (size_t)Bv * 4;        // 8

    cnn_kernel<<<Bv, 256, 0, stream>>>(x, w1, b1, w2, b2, pm, stats);
    quantum_kernel<<<(Bv * 16 + 255) / 256, 256, 0, stream>>>(
        pm, encp, qfcr, qfcp, qfeat, qraw, stats, Bv, g_ops);
    head_kernel<<<(Bv + 255) / 256, 256, 0, stream>>>(qfeat, qraw, stats, gam, bet,
                                                      fcw, fcb, out, Bv);
}